// Round 10
// baseline (3506.370 us; speedup 1.0000x reference)
//
#include <hip/hip_runtime.h>

// Problem constants (from reference setup_inputs / NUM_POINTS)
#define BATCH 16
#define NPTS  131072
#define NCH   6
#define KSEL  1024
#define MBLK  16                 // blocks per batch
#define TPB   512                // R10: 8 waves -> 2 waves/SIMD (TLP)
#define CHUNK (NPTS / MBLK)      // 8192 points per block
#define PPT   (CHUNK / TPB)      // 16 points per thread
#define NWAVE (TPB / 64)         // 8
#define ROT   2                  // slot rotation depth (double buffer)
#define LDSB  (3 * CHUNK * 4)    // 96 KB dynamic LDS: sx | sy | sz

// pub[BATCH][ROT][MBLK] u64 (4 KB), memset 0 before launch.
// Word: [dist_f32_bits:32][~idx:20][tag:12], tag = round k (1..1023 —
// 12-bit field never wraps; memset tag 0 never matches any polled round).
// All stores/loads RELAXED agent scope. u64 order: max dist first, then
// max ~idx = min global index — jnp.argmax first-occurrence tie-break.
// ROT=2 overwrite safety (causal): block A first overwrites slot (k&1) at
// round k+2, which requires A observed every block's round-(k+1) word; each
// block publishes k+1 only after finishing its round-k poll reads.
//
// R10 CHANGES vs R9 (regressed 2898->3259 despite FETCH 44->27.6 MB proving
// LDS residency landed; VALU time/round unchanged -> added stall):
//  1. Swizzle reverted to R8's proven b = blockIdx.x / MBLK mapping
//     (R9's %BATCH swizzle is regression suspect (a)).
//  2. TPB 256->512: at 96 KB LDS -> 1 block/CU, TPB=256 gave 1 wave/SIMD =
//     zero TLP, exposing every ds_read->VALU stall (suspect (b)). 8 waves
//     -> 2 waves/SIMD interleave, halving per-wave serial issue and hiding
//     LDS latency. PPT drops 32->16; reduce tree widens to 8 waves.

extern "C" __global__ __launch_bounds__(TPB)
void fps_kernel(const float* __restrict__ pts, float* __restrict__ out,
                unsigned long long* __restrict__ pub)
{
#pragma clang fp contract(off)
    extern __shared__ float sm[];            // sx[CHUNK] | sy[CHUNK] | sz[CHUNK]
    float* sx = sm;
    float* sy = sm + CHUNK;
    float* sz = sm + 2 * CHUNK;
    __shared__ float              s_wd[NWAVE];
    __shared__ int                s_wi[NWAVE];
    __shared__ unsigned long long s_key[MBLK];

    const int b    = blockIdx.x / MBLK;      // proven R8 mapping
    const int m    = blockIdx.x % MBLK;
    const int tid  = threadIdx.x;
    const int base = m * CHUNK;
    const float* __restrict__ pb = pts + (size_t)b * NPTS * NCH;

    // Stage this block's xyz chunk into LDS (SoA); dists in registers.
    float dmin[PPT];
#pragma unroll
    for (int i = 0; i < PPT; ++i) {
        const int idx = tid + i * TPB;
        const float* p = pb + (size_t)(base + idx) * NCH;
        sx[idx] = p[0];
        sy[idx] = p[1];
        sz[idx] = p[2];
        dmin[i] = __builtin_inff();
    }

    // Selected index 0 -> output row 0.
    if (m == 0 && tid < NCH) out[(size_t)b * KSEL * NCH + tid] = pb[tid];

    // p for round 1 is point 0 (uniform scalar loads of read-only data).
    float px = pb[0], py = pb[1], pz = pb[2];

    for (int k = 1; k < KSEL; ++k) {
        // ---- dist update + thread-local argmax (first-index tie-break) ----
        float bd = -1.0f;
        int   bj = 0;
#pragma unroll
        for (int i = 0; i < PPT; ++i) {
            const int idx = tid + i * TPB;
            // Bit-exact replication of the reference's f32 op sequence:
            // each op individually rounded (RN), no FMA / no reassociation.
            float dx = __fsub_rn(sx[idx], px);
            float dy = __fsub_rn(sy[idx], py);
            float dz = __fsub_rn(sz[idx], pz);
            float d  = __fadd_rn(__fadd_rn(__fmul_rn(dx, dx),
                                           __fmul_rn(dy, dy)),
                                 __fmul_rn(dz, dz));
            float dm = dmin[i];
            dm = (d < dm) ? d : dm;
            dmin[i] = dm;
            // idx ascends with i: strict '>' keeps first (smallest) index.
            if (dm > bd) { bd = dm; bj = idx; }
        }

        // ---- wave(64) argmax reduce, smaller index wins ties ----
        for (int off = 32; off > 0; off >>= 1) {
            float od = __shfl_down(bd, off);
            int   oj = __shfl_down(bj, off);
            if (od > bd || (od == bd && oj < bj)) { bd = od; bj = oj; }
        }
        if ((tid & 63) == 0) {
            const int w = tid >> 6;
            s_wd[w] = bd; s_wi[w] = bj;
        }
        __syncthreads();                                   // [A]

        unsigned long long* slot =
            pub + ((size_t)b * ROT + (size_t)(k & (ROT - 1))) * MBLK;

        // ---- publish this block's tagged key (tid 0) ----
        if (tid == 0) {
            float fd = s_wd[0]; int fi = s_wi[0];
#pragma unroll
            for (int w = 1; w < NWAVE; ++w) {
                if (s_wd[w] > fd || (s_wd[w] == fd && s_wi[w] < fi)) {
                    fd = s_wd[w]; fi = s_wi[w];
                }
            }
            const unsigned g   = (unsigned)(base + fi);
            const unsigned inv = 0xFFFFFu ^ g;             // 20-bit ~idx
            unsigned long long key =
                ((unsigned long long)__float_as_uint(fd) << 32)
                | ((unsigned long long)inv << 12)
                | (unsigned long long)(unsigned)k;         // 12-bit tag
            __hip_atomic_store(&slot[m], key, __ATOMIC_RELAXED,
                               __HIP_MEMORY_SCOPE_AGENT);
        }

        // ---- parallel poll: lane j waits for block j's word ----
        if (tid < MBLK) {
            unsigned long long v;
            do {
                v = __hip_atomic_load(&slot[tid], __ATOMIC_RELAXED,
                                      __HIP_MEMORY_SCOPE_AGENT);
            } while ((unsigned)(v & 0xFFFull) != (unsigned)k);
            s_key[tid] = v;
        }
        __syncthreads();                                   // [B]

        // ---- every thread: reduce 16 keys, fetch winner row (broadcast) ----
        // s_key reads precede next round's [A]; the poll rewrites s_key
        // only after [A] -> no race without a third barrier.
        unsigned long long mx = s_key[0];
#pragma unroll
        for (int w = 1; w < MBLK; ++w) {
            if (s_key[w] > mx) mx = s_key[w];
        }
        const unsigned g = 0xFFFFFu ^ (unsigned)((mx >> 12) & 0xFFFFFull);
        const float* pp = pb + (size_t)g * NCH;  // same addr all lanes: 1 txn
        px = pp[0]; py = pp[1]; pz = pp[2];

        // Round-robin writer block emits output row k.
        if ((k & (MBLK - 1)) == m && tid == 0) {
            float* o = out + ((size_t)b * KSEL + k) * NCH;
#pragma unroll
            for (int c = 0; c < NCH; ++c) o[c] = pp[c];
        }
    }
}

extern "C" void kernel_launch(void* const* d_in, const int* in_sizes, int n_in,
                              void* d_out, int out_size, void* d_ws, size_t ws_size,
                              hipStream_t stream) {
    const float* pts = (const float*)d_in[0];
    float* out = (float*)d_out;
    unsigned long long* pub = (unsigned long long*)d_ws;

    // pub[BATCH][ROT][MBLK] u64 = 4 KB; zero -> all tags 0 (never match).
    hipMemsetAsync(d_ws, 0,
                   (size_t)BATCH * ROT * MBLK * sizeof(unsigned long long),
                   stream);

    void* args[] = { (void*)&pts, (void*)&out, (void*)&pub };
    hipLaunchCooperativeKernel((const void*)fps_kernel,
                               dim3(BATCH * MBLK), dim3(TPB),
                               args, LDSB, stream);
}

// Round 12
// 2654.490 us; speedup vs baseline: 1.3209x; 1.3209x over previous
//
#include <hip/hip_runtime.h>

// Problem constants (from reference setup_inputs / NUM_POINTS)
#define BATCH 16
#define NPTS  131072
#define NCH   6
#define KSEL  1024
#define MBLK  16                 // blocks per batch
#define TPB   256
#define CHUNK (NPTS / MBLK)      // 8192 points per block
#define PPT   (CHUNK / TPB)      // 32 points per thread
#define NWAVE (TPB / 64)         // 4
#define ROT   2                  // slot rotation depth (double buffer)

// pub[BATCH][ROT][MBLK] u64 (4 KB), memset 0 before launch.
// Word: [dist_f32_bits:32][~idx:20][tag:12], tag = round k (1..1023 —
// 12-bit field never wraps; memset tag 0 never matches any polled round).
// All stores/loads RELAXED agent scope. u64 order: max dist first, then
// max ~idx = min global index — jnp.argmax first-occurrence tie-break.
// ROT=2 overwrite safety (causal): block A first overwrites slot (k&1) at
// round k+2, which requires A observed every block's round-(k+1) word; each
// block publishes k+1 only after finishing its round-k poll reads.
//
// R12 = R8's proven skeleton with ONE change: batch-per-XCD swizzle.
//   b = blockIdx.x % BATCH, m = blockIdx.x / BATCH
// -> all 16 blocks of batch b satisfy blockIdx.x ≡ b (mod 8), and dispatch
// assigns XCD round-robin by blockIdx, so the whole batch (publisher +
// all pollers + the winner-row broadcast) lives on ONE XCD. If agent-scope
// relaxed atomics are serviced XCD-locally, the publish->poll hop shrinks
// from die-level (~900 cyc) to XCD-L2 (~200-300 cyc). R9 hinted at this
// (FETCH 44->27.6 MB) but was confounded with the LDS-residency regression;
// this round isolates it. R8's asm-pins / waves_per_eu attr are dropped
// (R8 evidence: they only caused scratch spills, VGPR 96, dur-neutral).
// R5/R11 post-mortem: coord-carrying multi-word records kill the launch
// (stub signature twice) — banned; single-key publish only.

extern "C" __global__ __launch_bounds__(TPB)
void fps_kernel(const float* __restrict__ pts, float* __restrict__ out,
                unsigned long long* __restrict__ pub)
{
#pragma clang fp contract(off)
    __shared__ float              s_wd[NWAVE];
    __shared__ int                s_wi[NWAVE];
    __shared__ unsigned long long s_key[MBLK];

    const int b    = blockIdx.x % BATCH;     // batch-per-XCD swizzle
    const int m    = blockIdx.x / BATCH;
    const int tid  = threadIdx.x;
    const int base = m * CHUNK;
    const float* __restrict__ pb = pts + (size_t)b * NPTS * NCH;

    // Staging arrays: the compiler remats these loads into the k-loop and
    // streams coords from (now XCD-local) L2 each round with deep vmcnt
    // batching — measured faster than LDS or forced-register residency
    // (R8-R10). dmin stays a 32-VGPR loop-carried accumulator.
    float xr[PPT], yr[PPT], zr[PPT], dmin[PPT];
#pragma unroll
    for (int i = 0; i < PPT; ++i) {
        const float* p = pb + (size_t)(base + tid + i * TPB) * NCH;
        xr[i]   = p[0];
        yr[i]   = p[1];
        zr[i]   = p[2];
        dmin[i] = __builtin_inff();
    }

    // Selected index 0 -> output row 0.
    if (m == 0 && tid < NCH) out[(size_t)b * KSEL * NCH + tid] = pb[tid];

    // p for round 1 is point 0 (uniform scalar loads of read-only data).
    float px = pb[0], py = pb[1], pz = pb[2];

    for (int k = 1; k < KSEL; ++k) {
        // ---- dist update + thread-local argmax (first-index tie-break) ----
        float bd = -1.0f;
        int   bj = 0;
#pragma unroll
        for (int i = 0; i < PPT; ++i) {
            // Bit-exact replication of the reference's f32 op sequence:
            // each op individually rounded (RN), no FMA / no reassociation.
            float dx = __fsub_rn(xr[i], px);
            float dy = __fsub_rn(yr[i], py);
            float dz = __fsub_rn(zr[i], pz);
            float d  = __fadd_rn(__fadd_rn(__fmul_rn(dx, dx),
                                           __fmul_rn(dy, dy)),
                                 __fmul_rn(dz, dz));
            float dm = dmin[i];
            dm = (d < dm) ? d : dm;
            dmin[i] = dm;
            // j = tid + i*TPB ascends with i: strict '>' keeps first index.
            if (dm > bd) { bd = dm; bj = tid + i * TPB; }
        }

        // ---- wave(64) argmax reduce, smaller index wins ties ----
        for (int off = 32; off > 0; off >>= 1) {
            float od = __shfl_down(bd, off);
            int   oj = __shfl_down(bj, off);
            if (od > bd || (od == bd && oj < bj)) { bd = od; bj = oj; }
        }
        if ((tid & 63) == 0) {
            const int w = tid >> 6;
            s_wd[w] = bd; s_wi[w] = bj;
        }
        __syncthreads();                                   // [A]

        unsigned long long* slot =
            pub + ((size_t)b * ROT + (size_t)(k & (ROT - 1))) * MBLK;

        // ---- publish this block's tagged key (tid 0) ----
        if (tid == 0) {
            float fd = s_wd[0]; int fi = s_wi[0];
#pragma unroll
            for (int w = 1; w < NWAVE; ++w) {
                if (s_wd[w] > fd || (s_wd[w] == fd && s_wi[w] < fi)) {
                    fd = s_wd[w]; fi = s_wi[w];
                }
            }
            const unsigned g   = (unsigned)(base + fi);
            const unsigned inv = 0xFFFFFu ^ g;             // 20-bit ~idx
            unsigned long long key =
                ((unsigned long long)__float_as_uint(fd) << 32)
                | ((unsigned long long)inv << 12)
                | (unsigned long long)(unsigned)k;         // 12-bit tag
            __hip_atomic_store(&slot[m], key, __ATOMIC_RELAXED,
                               __HIP_MEMORY_SCOPE_AGENT);
        }

        // ---- parallel poll: lane j waits for block j's word ----
        if (tid < MBLK) {
            unsigned long long v;
            do {
                v = __hip_atomic_load(&slot[tid], __ATOMIC_RELAXED,
                                      __HIP_MEMORY_SCOPE_AGENT);
            } while ((unsigned)(v & 0xFFFull) != (unsigned)k);
            s_key[tid] = v;
        }
        __syncthreads();                                   // [B]

        // ---- every thread: reduce 16 keys, fetch winner row (broadcast) ----
        // s_key reads precede next round's [A]; the poll rewrites s_key
        // only after [A] -> no race without a third barrier.
        unsigned long long mx = s_key[0];
#pragma unroll
        for (int w = 1; w < MBLK; ++w) {
            if (s_key[w] > mx) mx = s_key[w];
        }
        const unsigned g = 0xFFFFFu ^ (unsigned)((mx >> 12) & 0xFFFFFull);
        const float* pp = pb + (size_t)g * NCH;  // same addr all lanes: 1 txn
        px = pp[0]; py = pp[1]; pz = pp[2];

        // Round-robin writer block emits output row k.
        if ((k & (MBLK - 1)) == m && tid == 0) {
            float* o = out + ((size_t)b * KSEL + k) * NCH;
#pragma unroll
            for (int c = 0; c < NCH; ++c) o[c] = pp[c];
        }
    }
}

extern "C" void kernel_launch(void* const* d_in, const int* in_sizes, int n_in,
                              void* d_out, int out_size, void* d_ws, size_t ws_size,
                              hipStream_t stream) {
    const float* pts = (const float*)d_in[0];
    float* out = (float*)d_out;
    unsigned long long* pub = (unsigned long long*)d_ws;

    // pub[BATCH][ROT][MBLK] u64 = 4 KB; zero -> all tags 0 (never match).
    hipMemsetAsync(d_ws, 0,
                   (size_t)BATCH * ROT * MBLK * sizeof(unsigned long long),
                   stream);

    void* args[] = { (void*)&pts, (void*)&out, (void*)&pub };
    hipLaunchCooperativeKernel((const void*)fps_kernel,
                               dim3(BATCH * MBLK), dim3(TPB),
                               args, 0, stream);
}